// Round 4
// baseline (1547.344 us; speedup 1.0000x reference)
//
#include <hip/hip_runtime.h>
#include <hip/hip_bf16.h>

constexpr int NN  = 50000;   // nodes
constexpr int NE  = 800000;  // edges
constexpr int DIM = 128;
constexpr int ROWS = 32;     // rows per GEMM block

// ---------------------------------------------------------------------------
// Detect whether edge_index was delivered as int64 (reference dtype) or int32
// (harness doc contract). If the buffer is int32, reading it as int64 yields
// lo | (hi<<32) with hi = the next index; hi==0 for all 64 probes is ~
// impossible, so "all values in [0, NN)" <=> genuine int64.
// ---------------------------------------------------------------------------
__global__ void detect_idx_width(const long long* __restrict__ ei, int* __restrict__ flag) {
    int is64 = 1;
    for (int i = 0; i < 64; ++i) {
        long long v = ei[i];
        if (v < 0 || v >= (long long)NN) { is64 = 0; break; }
    }
    *flag = is64;
}

// ---------------------------------------------------------------------------
// Scatter: acc[src[e]] += node_feats[dst[e]].  32 threads per edge, float4
// per thread (half-wave reads one contiguous 512B row slice).
// ---------------------------------------------------------------------------
__global__ __launch_bounds__(256) void scatter_add(const float* __restrict__ nf,
                                                   const void* __restrict__ eiv,
                                                   const int* __restrict__ flag,
                                                   float* __restrict__ acc) {
    const long long t = (long long)blockIdx.x * 256 + threadIdx.x;
    const int e = (int)(t >> 5);
    if (e >= NE) return;
    const int l = (int)(t & 31);

    int s, d;
    if (*flag) {
        const long long* ei = (const long long*)eiv;
        s = (int)ei[e];
        d = (int)ei[NE + e];
    } else {
        const int* ei = (const int*)eiv;
        s = ei[e];
        d = ei[NE + e];
    }

    const float4 v = *reinterpret_cast<const float4*>(nf + (size_t)d * DIM + l * 4);
    float* a = acc + (size_t)s * DIM + l * 4;
    atomicAdd(a + 0, v.x);
    atomicAdd(a + 1, v.y);
    atomicAdd(a + 2, v.z);
    atomicAdd(a + 3, v.w);
}

// ---------------------------------------------------------------------------
// Fused epilogue: out = nf @ self_w + tanh(acc @ nbr_w + b)
// Weights staged to LDS as bf16 (64 KB), 32 rows of acc/nf staged fp32 with
// +1 padding (33 KB). 256 threads; each owns a 2-row x 8-col output tile.
// acc may alias out (rows are staged before being overwritten).
// ---------------------------------------------------------------------------
static __device__ inline unsigned short f2bf(float x) {
    union { float f; unsigned int u; } c; c.f = x;
    unsigned int r = (c.u + 0x7fffu + ((c.u >> 16) & 1u)) >> 16;
    return (unsigned short)r;
}
static __device__ inline float bflo(unsigned int u) { return __uint_as_float(u << 16); }
static __device__ inline float bfhi(unsigned int u) { return __uint_as_float(u & 0xffff0000u); }

__global__ __launch_bounds__(256) void fused_gemm(const float* __restrict__ nf,
                                                  const float* __restrict__ acc,
                                                  const float* __restrict__ wn,
                                                  const float* __restrict__ wsf,
                                                  const float* __restrict__ bias,
                                                  float* __restrict__ out) {
    __shared__ unsigned short wn_l[DIM * DIM];   // [k][j] bf16 bits, 32 KB
    __shared__ unsigned short ws_l[DIM * DIM];   // 32 KB
    __shared__ float acc_l[ROWS][DIM + 1];       // +1 pad: conflict-free column reads
    __shared__ float nf_l[ROWS][DIM + 1];

    const int tid  = threadIdx.x;
    const int row0 = blockIdx.x * ROWS;

    // Stage weights: fp32 global -> bf16 LDS (4096 float4s each)
    for (int i = tid; i < DIM * DIM / 4; i += 256) {
        float4 a = reinterpret_cast<const float4*>(wn)[i];
        float4 b = reinterpret_cast<const float4*>(wsf)[i];
        wn_l[i * 4 + 0] = f2bf(a.x); wn_l[i * 4 + 1] = f2bf(a.y);
        wn_l[i * 4 + 2] = f2bf(a.z); wn_l[i * 4 + 3] = f2bf(a.w);
        ws_l[i * 4 + 0] = f2bf(b.x); ws_l[i * 4 + 1] = f2bf(b.y);
        ws_l[i * 4 + 2] = f2bf(b.z); ws_l[i * 4 + 3] = f2bf(b.w);
    }
    // Stage 32 rows of acc and nf (fp32)
    for (int i = tid; i < ROWS * DIM / 4; i += 256) {
        const int r  = i >> 5;       // 32 float4 per row
        const int c4 = i & 31;
        const int row = row0 + r;
        float4 va = make_float4(0.f, 0.f, 0.f, 0.f), vn = va;
        if (row < NN) {
            va = *reinterpret_cast<const float4*>(acc + (size_t)row * DIM + c4 * 4);
            vn = *reinterpret_cast<const float4*>(nf  + (size_t)row * DIM + c4 * 4);
        }
        acc_l[r][c4 * 4 + 0] = va.x; acc_l[r][c4 * 4 + 1] = va.y;
        acc_l[r][c4 * 4 + 2] = va.z; acc_l[r][c4 * 4 + 3] = va.w;
        nf_l[r][c4 * 4 + 0]  = vn.x; nf_l[r][c4 * 4 + 1]  = vn.y;
        nf_l[r][c4 * 4 + 2]  = vn.z; nf_l[r][c4 * 4 + 3]  = vn.w;
    }
    __syncthreads();

    const int j0 = (tid & 15) * 8;   // 8 output columns
    const int r0 = (tid >> 4) * 2;   // 2 output rows

    float an[2][8] = {};
    float as[2][8] = {};

#pragma unroll 4
    for (int k = 0; k < DIM; ++k) {
        const uint4 w4n = *reinterpret_cast<const uint4*>(&wn_l[k * DIM + j0]);
        const uint4 w4s = *reinterpret_cast<const uint4*>(&ws_l[k * DIM + j0]);
        float wnv[8], wsv[8];
        wnv[0] = bflo(w4n.x); wnv[1] = bfhi(w4n.x); wnv[2] = bflo(w4n.y); wnv[3] = bfhi(w4n.y);
        wnv[4] = bflo(w4n.z); wnv[5] = bfhi(w4n.z); wnv[6] = bflo(w4n.w); wnv[7] = bfhi(w4n.w);
        wsv[0] = bflo(w4s.x); wsv[1] = bfhi(w4s.x); wsv[2] = bflo(w4s.y); wsv[3] = bfhi(w4s.y);
        wsv[4] = bflo(w4s.z); wsv[5] = bfhi(w4s.z); wsv[6] = bflo(w4s.w); wsv[7] = bfhi(w4s.w);

        const float a0 = acc_l[r0][k],     a1 = acc_l[r0 + 1][k];
        const float n0 = nf_l[r0][k],      n1 = nf_l[r0 + 1][k];
#pragma unroll
        for (int c = 0; c < 8; ++c) {
            an[0][c] += a0 * wnv[c];
            an[1][c] += a1 * wnv[c];
            as[0][c] += n0 * wsv[c];
            as[1][c] += n1 * wsv[c];
        }
    }

    float bv[8];
#pragma unroll
    for (int c = 0; c < 8; ++c) bv[c] = bias[j0 + c];

#pragma unroll
    for (int h = 0; h < 2; ++h) {
        const int row = row0 + r0 + h;
        if (row >= NN) continue;
        float o[8];
#pragma unroll
        for (int c = 0; c < 8; ++c) o[c] = as[h][c] + tanhf(an[h][c] + bv[c]);
        float4* dst = reinterpret_cast<float4*>(out + (size_t)row * DIM + j0);
        dst[0] = make_float4(o[0], o[1], o[2], o[3]);
        dst[1] = make_float4(o[4], o[5], o[6], o[7]);
    }
}

extern "C" void kernel_launch(void* const* d_in, const int* in_sizes, int n_in,
                              void* d_out, int out_size, void* d_ws, size_t ws_size,
                              hipStream_t stream) {
    const float* nf  = (const float*)d_in[0];
    const void*  ei  = d_in[1];
    const float* wn  = (const float*)d_in[2];
    const float* wsf = (const float*)d_in[3];
    const float* bia = (const float*)d_in[4];
    float* out = (float*)d_out;
    int* flag = (int*)d_ws;

    detect_idx_width<<<1, 1, 0, stream>>>((const long long*)ei, flag);
    hipMemsetAsync(out, 0, (size_t)NN * DIM * sizeof(float), stream);

    const int scatter_blocks = (NE * 32) / 256;  // 100000
    scatter_add<<<scatter_blocks, 256, 0, stream>>>(nf, ei, flag, out);

    const int gemm_blocks = (NN + ROWS - 1) / ROWS;  // 1563
    fused_gemm<<<gemm_blocks, 256, 0, stream>>>(nf, out, wn, wsf, bia, out);
}

// Round 9
// 416.548 us; speedup vs baseline: 3.7147x; 3.7147x over previous
//
#include <hip/hip_runtime.h>
#include <hip/hip_bf16.h>

constexpr int NN   = 50000;   // nodes
constexpr int NE   = 800000;  // edges
constexpr int DIM  = 128;
constexpr int GROWS = 64;     // rows per fused_gemm block

// ws layout (CSR path): off[50004] | sorted_dst[800000] | flag[1]   (ints)
constexpr int OFF_I    = 0;
constexpr int SORT_I   = 50004;            // 16B-aligned
constexpr int FLAG_I   = 50004 + NE;       // 850004
constexpr size_t WS_REQ = (size_t)(FLAG_I + 1) * 4;  // 3,400,020 B

// ---------------------------------------------------------------------------
// int64 vs int32 edge-index detection (validated round 4). flag=1 => int64.
// ---------------------------------------------------------------------------
__global__ void detect_idx_width(const long long* __restrict__ ei, int* __restrict__ flag) {
    int is64 = 1;
    for (int i = 0; i < 64; ++i) {
        long long v = ei[i];
        if (v < 0 || v >= (long long)NN) { is64 = 0; break; }
    }
    *flag = is64;
}

__device__ inline int load_idx(const void* eiv, int is64, int pos) {
    return is64 ? (int)((const long long*)eiv)[pos] : ((const int*)eiv)[pos];
}

// ---------------------------------------------------------------------------
// CSR build: histogram of src -> exclusive scan -> fill sorted dst list.
// ---------------------------------------------------------------------------
__global__ __launch_bounds__(256) void edge_hist(const void* __restrict__ eiv,
                                                 const int* __restrict__ flag,
                                                 int* __restrict__ off) {
    const int e = blockIdx.x * 256 + threadIdx.x;
    if (e >= NE) return;
    const int s = load_idx(eiv, *flag, e);
    atomicAdd(&off[s], 1);
}

// Single-block exclusive scan over off[0..NN] (in place). 1024 threads,
// 49 contiguous elements each; one Hillis-Steele pass over 1024 partials.
__global__ __launch_bounds__(1024) void scan_off(int* __restrict__ off) {
    __shared__ int sh[1024];
    const int t = threadIdx.x;
    const int C = 49;                      // 1024*49 = 50176 >= NN+1
    const int base = t * C;

    int sum = 0;
    for (int i = 0; i < C; ++i) {
        const int idx = base + i;
        if (idx <= NN) sum += off[idx];
    }
    sh[t] = sum;
    __syncthreads();
    for (int d = 1; d < 1024; d <<= 1) {
        int v = (t >= d) ? sh[t - d] : 0;
        __syncthreads();
        sh[t] += v;
        __syncthreads();
    }
    int run = sh[t] - sum;                 // exclusive prefix for this chunk
    for (int i = 0; i < C; ++i) {
        const int idx = base + i;
        if (idx <= NN) {
            const int v = off[idx];
            off[idx] = run;
            run += v;
        }
    }
}

// After fill, off[s] = end of segment s; start = (s==0) ? 0 : off[s-1].
__global__ __launch_bounds__(256) void edge_fill(const void* __restrict__ eiv,
                                                 const int* __restrict__ flag,
                                                 int* __restrict__ off,
                                                 int* __restrict__ sorted) {
    const int e = blockIdx.x * 256 + threadIdx.x;
    if (e >= NE) return;
    const int is64 = *flag;
    const int s = load_idx(eiv, is64, e);
    const int d = load_idx(eiv, is64, NE + e);
    const int pos = atomicAdd(&off[s], 1);
    sorted[pos] = d;
}

// ---------------------------------------------------------------------------
// Atomic-free segment sum: one wave per node, lane owns 2 floats (8B x 64
// lanes = 512B row). 4-way unrolled neighbor loop for MLP.
// ---------------------------------------------------------------------------
__global__ __launch_bounds__(256) void gather_sum(const float* __restrict__ nf,
                                                  const int* __restrict__ off,
                                                  const int* __restrict__ sorted,
                                                  float* __restrict__ out) {
    const int node = blockIdx.x * 4 + (threadIdx.x >> 6);
    if (node >= NN) return;
    const int c = (threadIdx.x & 63) * 2;

    const int start = (node == 0) ? 0 : off[node - 1];
    const int end   = off[node];

    float sx = 0.f, sy = 0.f;
    int i = start;
    for (; i + 4 <= end; i += 4) {
        const int d0 = sorted[i], d1 = sorted[i + 1], d2 = sorted[i + 2], d3 = sorted[i + 3];
        const float2 v0 = *(const float2*)(nf + (size_t)d0 * DIM + c);
        const float2 v1 = *(const float2*)(nf + (size_t)d1 * DIM + c);
        const float2 v2 = *(const float2*)(nf + (size_t)d2 * DIM + c);
        const float2 v3 = *(const float2*)(nf + (size_t)d3 * DIM + c);
        sx += v0.x + v1.x + v2.x + v3.x;
        sy += v0.y + v1.y + v2.y + v3.y;
    }
    for (; i < end; ++i) {
        const float2 v = *(const float2*)(nf + (size_t)sorted[i] * DIM + c);
        sx += v.x; sy += v.y;
    }
    *(float2*)(out + (size_t)node * DIM + c) = make_float2(sx, sy);
}

// ---------------------------------------------------------------------------
// Fallback scatter (atomic) if ws_size is too small for CSR.
// ---------------------------------------------------------------------------
__global__ __launch_bounds__(256) void scatter_add(const float* __restrict__ nf,
                                                   const void* __restrict__ eiv,
                                                   const int* __restrict__ flag,
                                                   float* __restrict__ acc) {
    const long long t = (long long)blockIdx.x * 256 + threadIdx.x;
    const int e = (int)(t >> 5);
    if (e >= NE) return;
    const int l = (int)(t & 31);
    const int is64 = *flag;
    const int s = load_idx(eiv, is64, e);
    const int d = load_idx(eiv, is64, NE + e);
    const float4 v = *reinterpret_cast<const float4*>(nf + (size_t)d * DIM + l * 4);
    float* a = acc + (size_t)s * DIM + l * 4;
    atomicAdd(a + 0, v.x);
    atomicAdd(a + 1, v.y);
    atomicAdd(a + 2, v.z);
    atomicAdd(a + 3, v.w);
}

// ---------------------------------------------------------------------------
// out = nf @ self_w + tanh(acc @ nbr_w + b)
// v3: validated baseline structure (row-major fp32 tiles [r][k], broadcast
// reads are conflict-free), widened to 64 rows / 512 threads. LDS: 64KB bf16
// weights + 2 x [64][129] fp32 tiles = 131.6 KB -> 1 block/CU, 2 waves/SIMD.
// acc may alias out (rows staged to LDS before overwrite; block-private rows).
// ---------------------------------------------------------------------------
static __device__ inline unsigned short f2bf(float x) {
    union { float f; unsigned int u; } c; c.f = x;
    unsigned int r = (c.u + 0x7fffu + ((c.u >> 16) & 1u)) >> 16;
    return (unsigned short)r;
}
static __device__ inline float bflo(unsigned int u) { return __uint_as_float(u << 16); }
static __device__ inline float bfhi(unsigned int u) { return __uint_as_float(u & 0xffff0000u); }

__global__ __launch_bounds__(512) void fused_gemm(const float* __restrict__ nf,
                                                  const float* __restrict__ acc,
                                                  const float* __restrict__ wn,
                                                  const float* __restrict__ wsf,
                                                  const float* __restrict__ bias,
                                                  float* __restrict__ out) {
    __shared__ unsigned short wn_l[DIM * DIM];   // [k][j] bf16, 32 KB
    __shared__ unsigned short ws_l[DIM * DIM];   // 32 KB
    __shared__ float acc_l[GROWS][DIM + 1];      // [r][k] fp32, 33 KB
    __shared__ float nf_l[GROWS][DIM + 1];       // 33 KB

    const int tid  = threadIdx.x;
    const int row0 = blockIdx.x * GROWS;

    // Stage weights fp32 -> bf16 LDS (4096 float4 each, 8 iters @512 thr)
    for (int i = tid; i < DIM * DIM / 4; i += 512) {
        float4 a = reinterpret_cast<const float4*>(wn)[i];
        float4 b = reinterpret_cast<const float4*>(wsf)[i];
        wn_l[i * 4 + 0] = f2bf(a.x); wn_l[i * 4 + 1] = f2bf(a.y);
        wn_l[i * 4 + 2] = f2bf(a.z); wn_l[i * 4 + 3] = f2bf(a.w);
        ws_l[i * 4 + 0] = f2bf(b.x); ws_l[i * 4 + 1] = f2bf(b.y);
        ws_l[i * 4 + 2] = f2bf(b.z); ws_l[i * 4 + 3] = f2bf(b.w);
    }
    // Stage 64 rows of acc/nf (fp32, row-major, +1 pad)
    for (int i = tid; i < GROWS * (DIM / 4); i += 512) {
        const int r  = i >> 5;            // 32 float4 per row -> r in [0,64)
        const int c4 = i & 31;
        const int row = row0 + r;
        float4 va = make_float4(0.f, 0.f, 0.f, 0.f), vn = va;
        if (row < NN) {
            va = *reinterpret_cast<const float4*>(acc + (size_t)row * DIM + c4 * 4);
            vn = *reinterpret_cast<const float4*>(nf  + (size_t)row * DIM + c4 * 4);
        }
        acc_l[r][c4 * 4 + 0] = va.x; acc_l[r][c4 * 4 + 1] = va.y;
        acc_l[r][c4 * 4 + 2] = va.z; acc_l[r][c4 * 4 + 3] = va.w;
        nf_l[r][c4 * 4 + 0]  = vn.x; nf_l[r][c4 * 4 + 1]  = vn.y;
        nf_l[r][c4 * 4 + 2]  = vn.z; nf_l[r][c4 * 4 + 3]  = vn.w;
    }
    __syncthreads();

    const int j0 = (tid & 15) * 8;        // 8 output columns
    const int r0 = (tid >> 4) * 2;        // 2 output rows (0..62)

    float an[2][8] = {};
    float as[2][8] = {};

#pragma unroll 4
    for (int k = 0; k < DIM; ++k) {
        const uint4 w4n = *reinterpret_cast<const uint4*>(&wn_l[k * DIM + j0]);
        const uint4 w4s = *reinterpret_cast<const uint4*>(&ws_l[k * DIM + j0]);
        float wnv[8], wsv[8];
        wnv[0] = bflo(w4n.x); wnv[1] = bfhi(w4n.x); wnv[2] = bflo(w4n.y); wnv[3] = bfhi(w4n.y);
        wnv[4] = bflo(w4n.z); wnv[5] = bfhi(w4n.z); wnv[6] = bflo(w4n.w); wnv[7] = bfhi(w4n.w);
        wsv[0] = bflo(w4s.x); wsv[1] = bfhi(w4s.x); wsv[2] = bflo(w4s.y); wsv[3] = bfhi(w4s.y);
        wsv[4] = bflo(w4s.z); wsv[5] = bfhi(w4s.z); wsv[6] = bflo(w4s.w); wsv[7] = bfhi(w4s.w);

        const float a0 = acc_l[r0][k], a1 = acc_l[r0 + 1][k];
        const float n0 = nf_l[r0][k],  n1 = nf_l[r0 + 1][k];
#pragma unroll
        for (int c = 0; c < 8; ++c) {
            an[0][c] += a0 * wnv[c];
            an[1][c] += a1 * wnv[c];
            as[0][c] += n0 * wsv[c];
            as[1][c] += n1 * wsv[c];
        }
    }

    float bv[8];
#pragma unroll
    for (int c = 0; c < 8; ++c) bv[c] = bias[j0 + c];

#pragma unroll
    for (int h = 0; h < 2; ++h) {
        const int row = row0 + r0 + h;
        if (row >= NN) continue;
        float o[8];
#pragma unroll
        for (int c = 0; c < 8; ++c) o[c] = as[h][c] + tanhf(an[h][c] + bv[c]);
        float4* dst = reinterpret_cast<float4*>(out + (size_t)row * DIM + j0);
        dst[0] = make_float4(o[0], o[1], o[2], o[3]);
        dst[1] = make_float4(o[4], o[5], o[6], o[7]);
    }
}

extern "C" void kernel_launch(void* const* d_in, const int* in_sizes, int n_in,
                              void* d_out, int out_size, void* d_ws, size_t ws_size,
                              hipStream_t stream) {
    const float* nf  = (const float*)d_in[0];
    const void*  ei  = d_in[1];
    const float* wn  = (const float*)d_in[2];
    const float* wsf = (const float*)d_in[3];
    const float* bia = (const float*)d_in[4];
    float* out = (float*)d_out;
    int* ws_i = (int*)d_ws;

    const int gemm_blocks = (NN + GROWS - 1) / GROWS;   // 782
    const int edge_blocks = (NE + 255) / 256;           // 3125

    if (ws_size >= WS_REQ) {
        // ---- CSR path: no float atomics ----
        int* off    = ws_i + OFF_I;
        int* sorted = ws_i + SORT_I;
        int* flag   = ws_i + FLAG_I;

        detect_idx_width<<<1, 1, 0, stream>>>((const long long*)ei, flag);
        hipMemsetAsync(off, 0, (size_t)(NN + 1) * sizeof(int), stream);
        edge_hist<<<edge_blocks, 256, 0, stream>>>(ei, flag, off);
        scan_off<<<1, 1024, 0, stream>>>(off);
        edge_fill<<<edge_blocks, 256, 0, stream>>>(ei, flag, off, sorted);
        gather_sum<<<(NN + 3) / 4, 256, 0, stream>>>(nf, off, sorted, out);
        fused_gemm<<<gemm_blocks, 512, 0, stream>>>(nf, out, wn, wsf, bia, out);
    } else {
        // ---- fallback: atomic scatter ----
        int* flag = ws_i;
        detect_idx_width<<<1, 1, 0, stream>>>((const long long*)ei, flag);
        hipMemsetAsync(out, 0, (size_t)NN * DIM * sizeof(float), stream);
        scatter_add<<<(NE * 32) / 256, 256, 0, stream>>>(nf, ei, flag, out);
        fused_gemm<<<gemm_blocks, 512, 0, stream>>>(nf, out, wn, wsf, bia, out);
    }
}

// Round 10
// 349.312 us; speedup vs baseline: 4.4297x; 1.1925x over previous
//
#include <hip/hip_runtime.h>
#include <hip/hip_bf16.h>

constexpr int NN   = 50000;   // nodes
constexpr int NE   = 800000;  // edges
constexpr int DIM  = 128;
constexpr int GROWS = 64;     // rows per fused_gemm block

// LDS row stride for bf16 tiles: 128 + 8 pad -> 272B; 16B-chunk index
// (row*17 + kgrp) & 7 spreads fragment reads across all 8 bank-quads.
constexpr int LDK = 136;

// ws layout (CSR path): off[50004] | sorted_dst[800000] | flag[1]   (ints)
constexpr int OFF_I    = 0;
constexpr int SORT_I   = 50004;            // 16B-aligned
constexpr int FLAG_I   = 50004 + NE;       // 850004
constexpr size_t WS_REQ = (size_t)(FLAG_I + 1) * 4;  // 3,400,020 B

typedef __attribute__((ext_vector_type(4))) float f32x4;
typedef __attribute__((ext_vector_type(8))) short bf16x8;

// ---------------------------------------------------------------------------
// int64 vs int32 edge-index detection (validated round 4). flag=1 => int64.
// ---------------------------------------------------------------------------
__global__ void detect_idx_width(const long long* __restrict__ ei, int* __restrict__ flag) {
    int is64 = 1;
    for (int i = 0; i < 64; ++i) {
        long long v = ei[i];
        if (v < 0 || v >= (long long)NN) { is64 = 0; break; }
    }
    *flag = is64;
}

__device__ inline int load_idx(const void* eiv, int is64, int pos) {
    return is64 ? (int)((const long long*)eiv)[pos] : ((const int*)eiv)[pos];
}

// ---------------------------------------------------------------------------
// CSR build: histogram of src -> exclusive scan -> fill sorted dst list.
// ---------------------------------------------------------------------------
__global__ __launch_bounds__(256) void edge_hist(const void* __restrict__ eiv,
                                                 const int* __restrict__ flag,
                                                 int* __restrict__ off) {
    const int e = blockIdx.x * 256 + threadIdx.x;
    if (e >= NE) return;
    const int s = load_idx(eiv, *flag, e);
    atomicAdd(&off[s], 1);
}

__global__ __launch_bounds__(1024) void scan_off(int* __restrict__ off) {
    __shared__ int sh[1024];
    const int t = threadIdx.x;
    const int C = 49;                      // 1024*49 = 50176 >= NN+1
    const int base = t * C;

    int sum = 0;
    for (int i = 0; i < C; ++i) {
        const int idx = base + i;
        if (idx <= NN) sum += off[idx];
    }
    sh[t] = sum;
    __syncthreads();
    for (int d = 1; d < 1024; d <<= 1) {
        int v = (t >= d) ? sh[t - d] : 0;
        __syncthreads();
        sh[t] += v;
        __syncthreads();
    }
    int run = sh[t] - sum;                 // exclusive prefix for this chunk
    for (int i = 0; i < C; ++i) {
        const int idx = base + i;
        if (idx <= NN) {
            const int v = off[idx];
            off[idx] = run;
            run += v;
        }
    }
}

__global__ __launch_bounds__(256) void edge_fill(const void* __restrict__ eiv,
                                                 const int* __restrict__ flag,
                                                 int* __restrict__ off,
                                                 int* __restrict__ sorted) {
    const int e = blockIdx.x * 256 + threadIdx.x;
    if (e >= NE) return;
    const int is64 = *flag;
    const int s = load_idx(eiv, is64, e);
    const int d = load_idx(eiv, is64, NE + e);
    const int pos = atomicAdd(&off[s], 1);
    sorted[pos] = d;
}

// ---------------------------------------------------------------------------
// Atomic-free segment sum: one wave per node, lane owns 2 floats.
// ---------------------------------------------------------------------------
__global__ __launch_bounds__(256) void gather_sum(const float* __restrict__ nf,
                                                  const int* __restrict__ off,
                                                  const int* __restrict__ sorted,
                                                  float* __restrict__ out) {
    const int node = blockIdx.x * 4 + (threadIdx.x >> 6);
    if (node >= NN) return;
    const int c = (threadIdx.x & 63) * 2;

    const int start = (node == 0) ? 0 : off[node - 1];
    const int end   = off[node];

    float sx = 0.f, sy = 0.f;
    int i = start;
    for (; i + 4 <= end; i += 4) {
        const int d0 = sorted[i], d1 = sorted[i + 1], d2 = sorted[i + 2], d3 = sorted[i + 3];
        const float2 v0 = *(const float2*)(nf + (size_t)d0 * DIM + c);
        const float2 v1 = *(const float2*)(nf + (size_t)d1 * DIM + c);
        const float2 v2 = *(const float2*)(nf + (size_t)d2 * DIM + c);
        const float2 v3 = *(const float2*)(nf + (size_t)d3 * DIM + c);
        sx += v0.x + v1.x + v2.x + v3.x;
        sy += v0.y + v1.y + v2.y + v3.y;
    }
    for (; i < end; ++i) {
        const float2 v = *(const float2*)(nf + (size_t)sorted[i] * DIM + c);
        sx += v.x; sy += v.y;
    }
    *(float2*)(out + (size_t)node * DIM + c) = make_float2(sx, sy);
}

// ---------------------------------------------------------------------------
// Fallback scatter (atomic) if ws_size is too small for CSR.
// ---------------------------------------------------------------------------
__global__ __launch_bounds__(256) void scatter_add(const float* __restrict__ nf,
                                                   const void* __restrict__ eiv,
                                                   const int* __restrict__ flag,
                                                   float* __restrict__ acc) {
    const long long t = (long long)blockIdx.x * 256 + threadIdx.x;
    const int e = (int)(t >> 5);
    if (e >= NE) return;
    const int l = (int)(t & 31);
    const int is64 = *flag;
    const int s = load_idx(eiv, is64, e);
    const int d = load_idx(eiv, is64, NE + e);
    const float4 v = *reinterpret_cast<const float4*>(nf + (size_t)d * DIM + l * 4);
    float* a = acc + (size_t)s * DIM + l * 4;
    atomicAdd(a + 0, v.x);
    atomicAdd(a + 1, v.y);
    atomicAdd(a + 2, v.z);
    atomicAdd(a + 3, v.w);
}

// ---------------------------------------------------------------------------
// out = nf @ self_w + tanh(acc @ nbr_w + b)  --- MFMA version.
// Weights staged TRANSPOSED (Wt[j][k]) bf16, tiles [r][k] bf16, both with
// LDK=136 row stride (pad kills the stride-256B bank trap). 8 waves; wave w
// owns rows (w&3)*16, cols (w>>2)*64; mfma_f32_16x16x32_bf16, C/D layout
// col=lane&15, row=(lane>>4)*4+reg (m89-verified). acc may alias out (tiles
// staged to LDS before the strictly-block-private rows are overwritten).
// ---------------------------------------------------------------------------
static __device__ inline unsigned short f2bf(float x) {
    union { float f; unsigned int u; } c; c.f = x;
    unsigned int r = (c.u + 0x7fffu + ((c.u >> 16) & 1u)) >> 16;
    return (unsigned short)r;
}

__global__ __launch_bounds__(512) void fused_gemm(const float* __restrict__ nf,
                                                  const float* __restrict__ acc,
                                                  const float* __restrict__ wn,
                                                  const float* __restrict__ wsf,
                                                  const float* __restrict__ bias,
                                                  float* __restrict__ out) {
    __shared__ unsigned short wn_t[DIM * LDK];    // Wt_n[j][k] bf16, 34 KB
    __shared__ unsigned short ws_t[DIM * LDK];    // Wt_s[j][k] bf16, 34 KB
    __shared__ unsigned short ac_t[GROWS * LDK];  // acc tile [r][k], 17 KB
    __shared__ unsigned short nf_t[GROWS * LDK];  // nf  tile [r][k], 17 KB

    const int tid  = threadIdx.x;
    const int row0 = blockIdx.x * GROWS;

    // ---- stage weights transposed: thread t -> column j = t&127, k-chunk
    // kc = (t>>7)*32. Reads coalesced across lanes (fixed k, consec j).
    {
        const int j  = tid & 127;
        const int kc = (tid >> 7) * 32;
        float vn[32], vs[32];
#pragma unroll
        for (int kk = 0; kk < 32; ++kk) {
            vn[kk] = wn [(size_t)(kc + kk) * DIM + j];
            vs[kk] = wsf[(size_t)(kc + kk) * DIM + j];
        }
        unsigned int pn[16], ps[16];
#pragma unroll
        for (int m = 0; m < 16; ++m) {
            pn[m] = (unsigned int)f2bf(vn[2 * m]) | ((unsigned int)f2bf(vn[2 * m + 1]) << 16);
            ps[m] = (unsigned int)f2bf(vs[2 * m]) | ((unsigned int)f2bf(vs[2 * m + 1]) << 16);
        }
#pragma unroll
        for (int m = 0; m < 4; ++m) {
            const int boff = j * (LDK * 2) + (kc + 8 * m) * 2;   // 16B-aligned
            *reinterpret_cast<uint4*>(reinterpret_cast<char*>(wn_t) + boff)
                = make_uint4(pn[4 * m], pn[4 * m + 1], pn[4 * m + 2], pn[4 * m + 3]);
            *reinterpret_cast<uint4*>(reinterpret_cast<char*>(ws_t) + boff)
                = make_uint4(ps[4 * m], ps[4 * m + 1], ps[4 * m + 2], ps[4 * m + 3]);
        }
    }

    // ---- stage acc/nf tiles (fp32 -> bf16), coalesced float4 reads
    for (int i = tid; i < GROWS * (DIM / 4); i += 512) {
        const int r  = i >> 5;            // 32 float4 per row
        const int c4 = i & 31;
        const int row = row0 + r;
        float4 va = make_float4(0.f, 0.f, 0.f, 0.f), vb = va;
        if (row < NN) {
            va = *reinterpret_cast<const float4*>(acc + (size_t)row * DIM + c4 * 4);
            vb = *reinterpret_cast<const float4*>(nf  + (size_t)row * DIM + c4 * 4);
        }
        uint2 pa, pb;
        pa.x = (unsigned int)f2bf(va.x) | ((unsigned int)f2bf(va.y) << 16);
        pa.y = (unsigned int)f2bf(va.z) | ((unsigned int)f2bf(va.w) << 16);
        pb.x = (unsigned int)f2bf(vb.x) | ((unsigned int)f2bf(vb.y) << 16);
        pb.y = (unsigned int)f2bf(vb.z) | ((unsigned int)f2bf(vb.w) << 16);
        const int boff = r * (LDK * 2) + c4 * 8;                 // 8B-aligned
        *reinterpret_cast<uint2*>(reinterpret_cast<char*>(ac_t) + boff) = pa;
        *reinterpret_cast<uint2*>(reinterpret_cast<char*>(nf_t) + boff) = pb;
    }
    __syncthreads();

    // ---- compute: 8 waves
    const int w  = tid >> 6;
    const int l  = tid & 63;
    const int lr = l & 15;                // A row / B col / D col
    const int lg = l >> 4;                // k-group (8 bf16 each)
    const int wr = (w & 3) * 16;          // row strip in tile
    const int wc = (w >> 2) * 64;         // col base

    f32x4 accA[4], accN[4];
#pragma unroll
    for (int jt = 0; jt < 4; ++jt) {
        accA[jt] = (f32x4){0.f, 0.f, 0.f, 0.f};
        accN[jt] = (f32x4){0.f, 0.f, 0.f, 0.f};
    }

#pragma unroll
    for (int k0 = 0; k0 < DIM; k0 += 32) {
        const int arow = wr + lr;
        const int aoff = arow * (LDK * 2) + (k0 + 8 * lg) * 2;
        const bf16x8 aA = *reinterpret_cast<const bf16x8*>(
            reinterpret_cast<const char*>(ac_t) + aoff);
        const bf16x8 aN = *reinterpret_cast<const bf16x8*>(
            reinterpret_cast<const char*>(nf_t) + aoff);
#pragma unroll
        for (int jt = 0; jt < 4; ++jt) {
            const int brow = wc + jt * 16 + lr;
            const int boff = brow * (LDK * 2) + (k0 + 8 * lg) * 2;
            const bf16x8 bW = *reinterpret_cast<const bf16x8*>(
                reinterpret_cast<const char*>(wn_t) + boff);
            accA[jt] = __builtin_amdgcn_mfma_f32_16x16x32_bf16(aA, bW, accA[jt], 0, 0, 0);
            const bf16x8 bS = *reinterpret_cast<const bf16x8*>(
                reinterpret_cast<const char*>(ws_t) + boff);
            accN[jt] = __builtin_amdgcn_mfma_f32_16x16x32_bf16(aN, bS, accN[jt], 0, 0, 0);
        }
    }

    // ---- epilogue: out[row][col] = self + tanh(nbr + b)
#pragma unroll
    for (int jt = 0; jt < 4; ++jt) {
        const int col = wc + jt * 16 + lr;
        const float bv = bias[col];
#pragma unroll
        for (int r = 0; r < 4; ++r) {
            const int grow = row0 + wr + lg * 4 + r;
            if (grow < NN)
                out[(size_t)grow * DIM + col] = accN[jt][r] + tanhf(accA[jt][r] + bv);
        }
    }
}

extern "C" void kernel_launch(void* const* d_in, const int* in_sizes, int n_in,
                              void* d_out, int out_size, void* d_ws, size_t ws_size,
                              hipStream_t stream) {
    const float* nf  = (const float*)d_in[0];
    const void*  ei  = d_in[1];
    const float* wn  = (const float*)d_in[2];
    const float* wsf = (const float*)d_in[3];
    const float* bia = (const float*)d_in[4];
    float* out = (float*)d_out;
    int* ws_i = (int*)d_ws;

    const int gemm_blocks = (NN + GROWS - 1) / GROWS;   // 782
    const int edge_blocks = (NE + 255) / 256;           // 3125

    if (ws_size >= WS_REQ) {
        // ---- CSR path: no float atomics ----
        int* off    = ws_i + OFF_I;
        int* sorted = ws_i + SORT_I;
        int* flag   = ws_i + FLAG_I;

        detect_idx_width<<<1, 1, 0, stream>>>((const long long*)ei, flag);
        hipMemsetAsync(off, 0, (size_t)(NN + 1) * sizeof(int), stream);
        edge_hist<<<edge_blocks, 256, 0, stream>>>(ei, flag, off);
        scan_off<<<1, 1024, 0, stream>>>(off);
        edge_fill<<<edge_blocks, 256, 0, stream>>>(ei, flag, off, sorted);
        gather_sum<<<(NN + 3) / 4, 256, 0, stream>>>(nf, off, sorted, out);
        fused_gemm<<<gemm_blocks, 512, 0, stream>>>(nf, out, wn, wsf, bia, out);
    } else {
        // ---- fallback: atomic scatter ----
        int* flag = ws_i;
        detect_idx_width<<<1, 1, 0, stream>>>((const long long*)ei, flag);
        hipMemsetAsync(out, 0, (size_t)NN * DIM * sizeof(float), stream);
        scatter_add<<<(NE * 32) / 256, 256, 0, stream>>>(nf, ei, flag, out);
        fused_gemm<<<gemm_blocks, 512, 0, stream>>>(nf, out, wn, wsf, bia, out);
    }
}

// Round 13
// 269.744 us; speedup vs baseline: 5.7363x; 1.2950x over previous
//
#include <hip/hip_runtime.h>
#include <hip/hip_bf16.h>

constexpr int NN   = 50000;   // nodes
constexpr int NE   = 800000;  // edges
constexpr int DIM  = 128;
constexpr int GROWS = 64;     // rows per fused_gemm block

// LDS row stride for bf16 tiles: 128 + 8 pad -> 272B; 16B-chunk index
// (row*17 + kgrp) & 7 spreads fragment reads across all 8 bank-quads.
constexpr int LDK = 136;

// scan geometry: 50001 elements in 196 blocks of 256
constexpr int SCAN_N   = NN + 1;                 // 50001
constexpr int SCAN_NPB = (SCAN_N + 255) / 256;   // 196

// ws layout (CSR path): off[50004] | sorted_dst[800000] | flag | partials[256]
constexpr int OFF_I    = 0;
constexpr int SORT_I   = 50004;            // 16B-aligned
constexpr int FLAG_I   = 50004 + NE;       // 850004
constexpr int PART_I   = FLAG_I + 1;       // 850005
constexpr size_t WS_REQ = (size_t)(PART_I + 256) * 4;  // ~3.4 MB

typedef __attribute__((ext_vector_type(4))) float f32x4;
typedef __attribute__((ext_vector_type(8))) short bf16x8;

// ---------------------------------------------------------------------------
// int64 vs int32 edge-index detection (validated round 4). flag=1 => int64.
// ---------------------------------------------------------------------------
__global__ void detect_idx_width(const long long* __restrict__ ei, int* __restrict__ flag) {
    int is64 = 1;
    for (int i = 0; i < 64; ++i) {
        long long v = ei[i];
        if (v < 0 || v >= (long long)NN) { is64 = 0; break; }
    }
    *flag = is64;
}

__device__ inline int load_idx(const void* eiv, int is64, int pos) {
    return is64 ? (int)((const long long*)eiv)[pos] : ((const int*)eiv)[pos];
}

// ---------------------------------------------------------------------------
// CSR build: histogram of src -> 3-pass exclusive scan -> fill sorted dst.
// ---------------------------------------------------------------------------
__global__ __launch_bounds__(256) void edge_hist(const void* __restrict__ eiv,
                                                 const int* __restrict__ flag,
                                                 int* __restrict__ off) {
    const int e = blockIdx.x * 256 + threadIdx.x;
    if (e >= NE) return;
    const int s = load_idx(eiv, *flag, e);
    atomicAdd(&off[s], 1);
}

// pass 1: per-block exclusive scan (coalesced), block totals -> partials
__global__ __launch_bounds__(256) void scan_blocks(int* __restrict__ off,
                                                   int* __restrict__ partials) {
    __shared__ int sh[256];
    const int t = threadIdx.x;
    const int i = blockIdx.x * 256 + t;
    const int v = (i < SCAN_N) ? off[i] : 0;
    sh[t] = v;
    __syncthreads();
    for (int d = 1; d < 256; d <<= 1) {
        const int u = (t >= d) ? sh[t - d] : 0;
        __syncthreads();
        sh[t] += u;
        __syncthreads();
    }
    if (i < SCAN_N) off[i] = sh[t] - v;           // exclusive
    if (t == 255) partials[blockIdx.x] = sh[255]; // block total
}

// pass 2: exclusive scan of the 196 block totals (single small block)
__global__ __launch_bounds__(256) void scan_partials(int* __restrict__ partials) {
    __shared__ int sh[256];
    const int t = threadIdx.x;
    const int v = (t < SCAN_NPB) ? partials[t] : 0;
    sh[t] = v;
    __syncthreads();
    for (int d = 1; d < 256; d <<= 1) {
        const int u = (t >= d) ? sh[t - d] : 0;
        __syncthreads();
        sh[t] += u;
        __syncthreads();
    }
    if (t < SCAN_NPB) partials[t] = sh[t] - v;    // exclusive
}

// pass 3: add block prefix
__global__ __launch_bounds__(256) void scan_add(int* __restrict__ off,
                                                const int* __restrict__ partials) {
    const int i = blockIdx.x * 256 + threadIdx.x;
    if (i < SCAN_N) off[i] += partials[blockIdx.x];
}

// After fill, off[s] = end of segment s; start = (s==0) ? 0 : off[s-1].
__global__ __launch_bounds__(256) void edge_fill(const void* __restrict__ eiv,
                                                 const int* __restrict__ flag,
                                                 int* __restrict__ off,
                                                 int* __restrict__ sorted) {
    const int e = blockIdx.x * 256 + threadIdx.x;
    if (e >= NE) return;
    const int is64 = *flag;
    const int s = load_idx(eiv, is64, e);
    const int d = load_idx(eiv, is64, NE + e);
    const int pos = atomicAdd(&off[s], 1);
    sorted[pos] = d;
}

// ---------------------------------------------------------------------------
// Atomic-free segment sum: one wave per node, lane owns 2 floats.
// ---------------------------------------------------------------------------
__global__ __launch_bounds__(256) void gather_sum(const float* __restrict__ nf,
                                                  const int* __restrict__ off,
                                                  const int* __restrict__ sorted,
                                                  float* __restrict__ out) {
    const int node = blockIdx.x * 4 + (threadIdx.x >> 6);
    if (node >= NN) return;
    const int c = (threadIdx.x & 63) * 2;

    const int start = (node == 0) ? 0 : off[node - 1];
    const int end   = off[node];

    float sx = 0.f, sy = 0.f;
    int i = start;
    for (; i + 4 <= end; i += 4) {
        const int d0 = sorted[i], d1 = sorted[i + 1], d2 = sorted[i + 2], d3 = sorted[i + 3];
        const float2 v0 = *(const float2*)(nf + (size_t)d0 * DIM + c);
        const float2 v1 = *(const float2*)(nf + (size_t)d1 * DIM + c);
        const float2 v2 = *(const float2*)(nf + (size_t)d2 * DIM + c);
        const float2 v3 = *(const float2*)(nf + (size_t)d3 * DIM + c);
        sx += v0.x + v1.x + v2.x + v3.x;
        sy += v0.y + v1.y + v2.y + v3.y;
    }
    for (; i < end; ++i) {
        const float2 v = *(const float2*)(nf + (size_t)sorted[i] * DIM + c);
        sx += v.x; sy += v.y;
    }
    *(float2*)(out + (size_t)node * DIM + c) = make_float2(sx, sy);
}

// ---------------------------------------------------------------------------
// Fallback scatter (atomic) if ws_size is too small for CSR.
// ---------------------------------------------------------------------------
__global__ __launch_bounds__(256) void scatter_add(const float* __restrict__ nf,
                                                   const void* __restrict__ eiv,
                                                   const int* __restrict__ flag,
                                                   float* __restrict__ acc) {
    const long long t = (long long)blockIdx.x * 256 + threadIdx.x;
    const int e = (int)(t >> 5);
    if (e >= NE) return;
    const int l = (int)(t & 31);
    const int is64 = *flag;
    const int s = load_idx(eiv, is64, e);
    const int d = load_idx(eiv, is64, NE + e);
    const float4 v = *reinterpret_cast<const float4*>(nf + (size_t)d * DIM + l * 4);
    float* a = acc + (size_t)s * DIM + l * 4;
    atomicAdd(a + 0, v.x);
    atomicAdd(a + 1, v.y);
    atomicAdd(a + 2, v.z);
    atomicAdd(a + 3, v.w);
}

// ---------------------------------------------------------------------------
// out = nf @ self_w + tanh(acc @ nbr_w + b)  --- MFMA version (validated r10).
// ---------------------------------------------------------------------------
static __device__ inline unsigned short f2bf(float x) {
    union { float f; unsigned int u; } c; c.f = x;
    unsigned int r = (c.u + 0x7fffu + ((c.u >> 16) & 1u)) >> 16;
    return (unsigned short)r;
}

__global__ __launch_bounds__(512) void fused_gemm(const float* __restrict__ nf,
                                                  const float* __restrict__ acc,
                                                  const float* __restrict__ wn,
                                                  const float* __restrict__ wsf,
                                                  const float* __restrict__ bias,
                                                  float* __restrict__ out) {
    __shared__ unsigned short wn_t[DIM * LDK];    // Wt_n[j][k] bf16, 34 KB
    __shared__ unsigned short ws_t[DIM * LDK];    // Wt_s[j][k] bf16, 34 KB
    __shared__ unsigned short ac_t[GROWS * LDK];  // acc tile [r][k], 17 KB
    __shared__ unsigned short nf_t[GROWS * LDK];  // nf  tile [r][k], 17 KB

    const int tid  = threadIdx.x;
    const int row0 = blockIdx.x * GROWS;

    // ---- stage weights transposed: thread t -> column j = t&127, k-chunk
    {
        const int j  = tid & 127;
        const int kc = (tid >> 7) * 32;
        float vn[32], vs[32];
#pragma unroll
        for (int kk = 0; kk < 32; ++kk) {
            vn[kk] = wn [(size_t)(kc + kk) * DIM + j];
            vs[kk] = wsf[(size_t)(kc + kk) * DIM + j];
        }
        unsigned int pn[16], ps[16];
#pragma unroll
        for (int m = 0; m < 16; ++m) {
            pn[m] = (unsigned int)f2bf(vn[2 * m]) | ((unsigned int)f2bf(vn[2 * m + 1]) << 16);
            ps[m] = (unsigned int)f2bf(vs[2 * m]) | ((unsigned int)f2bf(vs[2 * m + 1]) << 16);
        }
#pragma unroll
        for (int m = 0; m < 4; ++m) {
            const int boff = j * (LDK * 2) + (kc + 8 * m) * 2;   // 16B-aligned
            *reinterpret_cast<uint4*>(reinterpret_cast<char*>(wn_t) + boff)
                = make_uint4(pn[4 * m], pn[4 * m + 1], pn[4 * m + 2], pn[4 * m + 3]);
            *reinterpret_cast<uint4*>(reinterpret_cast<char*>(ws_t) + boff)
                = make_uint4(ps[4 * m], ps[4 * m + 1], ps[4 * m + 2], ps[4 * m + 3]);
        }
    }

    // ---- stage acc/nf tiles (fp32 -> bf16), coalesced float4 reads
    for (int i = tid; i < GROWS * (DIM / 4); i += 512) {
        const int r  = i >> 5;            // 32 float4 per row
        const int c4 = i & 31;
        const int row = row0 + r;
        float4 va = make_float4(0.f, 0.f, 0.f, 0.f), vb = va;
        if (row < NN) {
            va = *reinterpret_cast<const float4*>(acc + (size_t)row * DIM + c4 * 4);
            vb = *reinterpret_cast<const float4*>(nf  + (size_t)row * DIM + c4 * 4);
        }
        uint2 pa, pb;
        pa.x = (unsigned int)f2bf(va.x) | ((unsigned int)f2bf(va.y) << 16);
        pa.y = (unsigned int)f2bf(va.z) | ((unsigned int)f2bf(va.w) << 16);
        pb.x = (unsigned int)f2bf(vb.x) | ((unsigned int)f2bf(vb.y) << 16);
        pb.y = (unsigned int)f2bf(vb.z) | ((unsigned int)f2bf(vb.w) << 16);
        const int boff = r * (LDK * 2) + c4 * 8;                 // 8B-aligned
        *reinterpret_cast<uint2*>(reinterpret_cast<char*>(ac_t) + boff) = pa;
        *reinterpret_cast<uint2*>(reinterpret_cast<char*>(nf_t) + boff) = pb;
    }
    __syncthreads();

    // ---- compute: 8 waves
    const int w  = tid >> 6;
    const int l  = tid & 63;
    const int lr = l & 15;                // A row / B col / D col
    const int lg = l >> 4;                // k-group (8 bf16 each)
    const int wr = (w & 3) * 16;          // row strip in tile
    const int wc = (w >> 2) * 64;         // col base

    f32x4 accA[4], accN[4];
#pragma unroll
    for (int jt = 0; jt < 4; ++jt) {
        accA[jt] = (f32x4){0.f, 0.f, 0.f, 0.f};
        accN[jt] = (f32x4){0.f, 0.f, 0.f, 0.f};
    }

#pragma unroll
    for (int k0 = 0; k0 < DIM; k0 += 32) {
        const int arow = wr + lr;
        const int aoff = arow * (LDK * 2) + (k0 + 8 * lg) * 2;
        const bf16x8 aA = *reinterpret_cast<const bf16x8*>(
            reinterpret_cast<const char*>(ac_t) + aoff);
        const bf16x8 aN = *reinterpret_cast<const bf16x8*>(
            reinterpret_cast<const char*>(nf_t) + aoff);
#pragma unroll
        for (int jt = 0; jt < 4; ++jt) {
            const int brow = wc + jt * 16 + lr;
            const int boff = brow * (LDK * 2) + (k0 + 8 * lg) * 2;
            const bf16x8 bW = *reinterpret_cast<const bf16x8*>(
                reinterpret_cast<const char*>(wn_t) + boff);
            accA[jt] = __builtin_amdgcn_mfma_f32_16x16x32_bf16(aA, bW, accA[jt], 0, 0, 0);
            const bf16x8 bS = *reinterpret_cast<const bf16x8*>(
                reinterpret_cast<const char*>(ws_t) + boff);
            accN[jt] = __builtin_amdgcn_mfma_f32_16x16x32_bf16(aN, bS, accN[jt], 0, 0, 0);
        }
    }

    // ---- epilogue: out[row][col] = self + tanh(nbr + b)
#pragma unroll
    for (int jt = 0; jt < 4; ++jt) {
        const int col = wc + jt * 16 + lr;
        const float bv = bias[col];
#pragma unroll
        for (int r = 0; r < 4; ++r) {
            const int grow = row0 + wr + lg * 4 + r;
            if (grow < NN)
                out[(size_t)grow * DIM + col] = accN[jt][r] + tanhf(accA[jt][r] + bv);
        }
    }
}

extern "C" void kernel_launch(void* const* d_in, const int* in_sizes, int n_in,
                              void* d_out, int out_size, void* d_ws, size_t ws_size,
                              hipStream_t stream) {
    const float* nf  = (const float*)d_in[0];
    const void*  ei  = d_in[1];
    const float* wn  = (const float*)d_in[2];
    const float* wsf = (const float*)d_in[3];
    const float* bia = (const float*)d_in[4];
    float* out = (float*)d_out;
    int* ws_i = (int*)d_ws;

    const int gemm_blocks = (NN + GROWS - 1) / GROWS;   // 782
    const int edge_blocks = (NE + 255) / 256;           // 3125

    if (ws_size >= WS_REQ) {
        // ---- CSR path: no float atomics ----
        int* off      = ws_i + OFF_I;
        int* sorted   = ws_i + SORT_I;
        int* flag     = ws_i + FLAG_I;
        int* partials = ws_i + PART_I;

        detect_idx_width<<<1, 1, 0, stream>>>((const long long*)ei, flag);
        hipMemsetAsync(off, 0, (size_t)(NN + 1) * sizeof(int), stream);
        edge_hist<<<edge_blocks, 256, 0, stream>>>(ei, flag, off);
        scan_blocks<<<SCAN_NPB, 256, 0, stream>>>(off, partials);
        scan_partials<<<1, 256, 0, stream>>>(partials);
        scan_add<<<SCAN_NPB, 256, 0, stream>>>(off, partials);
        edge_fill<<<edge_blocks, 256, 0, stream>>>(ei, flag, off, sorted);
        gather_sum<<<(NN + 3) / 4, 256, 0, stream>>>(nf, off, sorted, out);
        fused_gemm<<<gemm_blocks, 512, 0, stream>>>(nf, out, wn, wsf, bia, out);
    } else {
        // ---- fallback: atomic scatter ----
        int* flag = ws_i;
        detect_idx_width<<<1, 1, 0, stream>>>((const long long*)ei, flag);
        hipMemsetAsync(out, 0, (size_t)NN * DIM * sizeof(float), stream);
        scatter_add<<<(NE * 32) / 256, 256, 0, stream>>>(nf, ei, flag, out);
        fused_gemm<<<gemm_blocks, 512, 0, stream>>>(nf, out, wn, wsf, bia, out);
    }
}

// Round 14
// 257.053 us; speedup vs baseline: 6.0196x; 1.0494x over previous
//
#include <hip/hip_runtime.h>
#include <hip/hip_bf16.h>

constexpr int NN   = 50000;   // nodes
constexpr int NE   = 800000;  // edges
constexpr int DIM  = 128;
constexpr int GROWS = 64;     // rows per fused_gemm block

// LDS row stride for bf16 tiles: 128 + 8 pad -> 272B; 16B-chunk index
// (row*17 + kgrp) & 7 spreads fragment reads across all 8 bank-quads.
constexpr int LDK = 136;

// scan geometry: 50001 elements in 196 blocks of 256
constexpr int SCAN_N   = NN + 1;                 // 50001
constexpr int SCAN_NPB = (SCAN_N + 255) / 256;   // 196

// ws layout (CSR path): off[50004] | sorted_dst(ushort)[800000->400000 ints] |
//                       flag | partials[256]
constexpr int OFF_I    = 0;
constexpr int SORT_I   = 50004;            // 16B-aligned; ushort[800000] = 400000 ints
constexpr int FLAG_I   = SORT_I + NE / 2;  // 450004
constexpr int PART_I   = FLAG_I + 1;       // 450005
constexpr size_t WS_REQ = (size_t)(PART_I + 256) * 4;  // ~1.8 MB

typedef __attribute__((ext_vector_type(4))) float f32x4;
typedef __attribute__((ext_vector_type(8))) short bf16x8;

// ---------------------------------------------------------------------------
// int64 vs int32 edge-index detection (validated round 4). flag=1 => int64.
// ---------------------------------------------------------------------------
__global__ void detect_idx_width(const long long* __restrict__ ei, int* __restrict__ flag) {
    int is64 = 1;
    for (int i = 0; i < 64; ++i) {
        long long v = ei[i];
        if (v < 0 || v >= (long long)NN) { is64 = 0; break; }
    }
    *flag = is64;
}

__device__ inline int load_idx(const void* eiv, int is64, int pos) {
    return is64 ? (int)((const long long*)eiv)[pos] : ((const int*)eiv)[pos];
}

// ---------------------------------------------------------------------------
// CSR build: histogram of src -> 3-pass exclusive scan -> fill sorted dst.
// ---------------------------------------------------------------------------
__global__ __launch_bounds__(256) void edge_hist(const void* __restrict__ eiv,
                                                 const int* __restrict__ flag,
                                                 int* __restrict__ off) {
    const int e = blockIdx.x * 256 + threadIdx.x;
    if (e >= NE) return;
    const int s = load_idx(eiv, *flag, e);
    atomicAdd(&off[s], 1);
}

// pass 1: per-block exclusive scan (coalesced), block totals -> partials
__global__ __launch_bounds__(256) void scan_blocks(int* __restrict__ off,
                                                   int* __restrict__ partials) {
    __shared__ int sh[256];
    const int t = threadIdx.x;
    const int i = blockIdx.x * 256 + t;
    const int v = (i < SCAN_N) ? off[i] : 0;
    sh[t] = v;
    __syncthreads();
    for (int d = 1; d < 256; d <<= 1) {
        const int u = (t >= d) ? sh[t - d] : 0;
        __syncthreads();
        sh[t] += u;
        __syncthreads();
    }
    if (i < SCAN_N) off[i] = sh[t] - v;           // exclusive
    if (t == 255) partials[blockIdx.x] = sh[255]; // block total
}

// pass 2: exclusive scan of the 196 block totals (single small block)
__global__ __launch_bounds__(256) void scan_partials(int* __restrict__ partials) {
    __shared__ int sh[256];
    const int t = threadIdx.x;
    const int v = (t < SCAN_NPB) ? partials[t] : 0;
    sh[t] = v;
    __syncthreads();
    for (int d = 1; d < 256; d <<= 1) {
        const int u = (t >= d) ? sh[t - d] : 0;
        __syncthreads();
        sh[t] += u;
        __syncthreads();
    }
    if (t < SCAN_NPB) partials[t] = sh[t] - v;    // exclusive
}

// pass 3: add block prefix
__global__ __launch_bounds__(256) void scan_add(int* __restrict__ off,
                                                const int* __restrict__ partials) {
    const int i = blockIdx.x * 256 + threadIdx.x;
    if (i < SCAN_N) off[i] += partials[blockIdx.x];
}

// After fill, off[s] = end of segment s; start = (s==0) ? 0 : off[s-1].
// sorted[] is ushort (dst < 50000 < 65536): halves the scattered-write
// working set (25k lines vs 50k) -> less partial-line writeback amplification.
__global__ __launch_bounds__(256) void edge_fill(const void* __restrict__ eiv,
                                                 const int* __restrict__ flag,
                                                 int* __restrict__ off,
                                                 unsigned short* __restrict__ sorted) {
    const int e = blockIdx.x * 256 + threadIdx.x;
    if (e >= NE) return;
    const int is64 = *flag;
    const int s = load_idx(eiv, is64, e);
    const int d = load_idx(eiv, is64, NE + e);
    const int pos = atomicAdd(&off[s], 1);
    sorted[pos] = (unsigned short)d;
}

// ---------------------------------------------------------------------------
// Atomic-free segment sum v2: one HALF-WAVE (32 lanes) per node, float4/lane
// (32 x 16B = full 512B row per load instruction). 4-deep neighbor unroll
// keeps 4 row-loads outstanding. 256 thr = 4 waves = 8 nodes per block.
// ---------------------------------------------------------------------------
__global__ __launch_bounds__(256) void gather_sum(const float* __restrict__ nf,
                                                  const int* __restrict__ off,
                                                  const unsigned short* __restrict__ sorted,
                                                  float* __restrict__ out) {
    const int node = blockIdx.x * 8 + ((threadIdx.x >> 6) << 1) + ((threadIdx.x >> 5) & 1);
    if (node >= NN) return;
    const int c = (threadIdx.x & 31) * 4;

    const int start = (node == 0) ? 0 : off[node - 1];
    const int end   = off[node];

    float4 s = make_float4(0.f, 0.f, 0.f, 0.f);
    int i = start;
    for (; i + 4 <= end; i += 4) {
        const int d0 = sorted[i], d1 = sorted[i + 1], d2 = sorted[i + 2], d3 = sorted[i + 3];
        const float4 v0 = *(const float4*)(nf + (size_t)d0 * DIM + c);
        const float4 v1 = *(const float4*)(nf + (size_t)d1 * DIM + c);
        const float4 v2 = *(const float4*)(nf + (size_t)d2 * DIM + c);
        const float4 v3 = *(const float4*)(nf + (size_t)d3 * DIM + c);
        s.x += v0.x + v1.x + v2.x + v3.x;
        s.y += v0.y + v1.y + v2.y + v3.y;
        s.z += v0.z + v1.z + v2.z + v3.z;
        s.w += v0.w + v1.w + v2.w + v3.w;
    }
    for (; i < end; ++i) {
        const float4 v = *(const float4*)(nf + (size_t)sorted[i] * DIM + c);
        s.x += v.x; s.y += v.y; s.z += v.z; s.w += v.w;
    }
    *(float4*)(out + (size_t)node * DIM + c) = s;
}

// ---------------------------------------------------------------------------
// Fallback scatter (atomic) if ws_size is too small for CSR.
// ---------------------------------------------------------------------------
__global__ __launch_bounds__(256) void scatter_add(const float* __restrict__ nf,
                                                   const void* __restrict__ eiv,
                                                   const int* __restrict__ flag,
                                                   float* __restrict__ acc) {
    const long long t = (long long)blockIdx.x * 256 + threadIdx.x;
    const int e = (int)(t >> 5);
    if (e >= NE) return;
    const int l = (int)(t & 31);
    const int is64 = *flag;
    const int s = load_idx(eiv, is64, e);
    const int d = load_idx(eiv, is64, NE + e);
    const float4 v = *reinterpret_cast<const float4*>(nf + (size_t)d * DIM + l * 4);
    float* a = acc + (size_t)s * DIM + l * 4;
    atomicAdd(a + 0, v.x);
    atomicAdd(a + 1, v.y);
    atomicAdd(a + 2, v.z);
    atomicAdd(a + 3, v.w);
}

// ---------------------------------------------------------------------------
// out = nf @ self_w + tanh(acc @ nbr_w + b)  --- MFMA version (validated r10).
// ---------------------------------------------------------------------------
static __device__ inline unsigned short f2bf(float x) {
    union { float f; unsigned int u; } c; c.f = x;
    unsigned int r = (c.u + 0x7fffu + ((c.u >> 16) & 1u)) >> 16;
    return (unsigned short)r;
}

__global__ __launch_bounds__(512) void fused_gemm(const float* __restrict__ nf,
                                                  const float* __restrict__ acc,
                                                  const float* __restrict__ wn,
                                                  const float* __restrict__ wsf,
                                                  const float* __restrict__ bias,
                                                  float* __restrict__ out) {
    __shared__ unsigned short wn_t[DIM * LDK];    // Wt_n[j][k] bf16, 34 KB
    __shared__ unsigned short ws_t[DIM * LDK];    // Wt_s[j][k] bf16, 34 KB
    __shared__ unsigned short ac_t[GROWS * LDK];  // acc tile [r][k], 17 KB
    __shared__ unsigned short nf_t[GROWS * LDK];  // nf  tile [r][k], 17 KB

    const int tid  = threadIdx.x;
    const int row0 = blockIdx.x * GROWS;

    // ---- stage weights transposed: thread t -> column j = t&127, k-chunk
    {
        const int j  = tid & 127;
        const int kc = (tid >> 7) * 32;
        float vn[32], vs[32];
#pragma unroll
        for (int kk = 0; kk < 32; ++kk) {
            vn[kk] = wn [(size_t)(kc + kk) * DIM + j];
            vs[kk] = wsf[(size_t)(kc + kk) * DIM + j];
        }
        unsigned int pn[16], ps[16];
#pragma unroll
        for (int m = 0; m < 16; ++m) {
            pn[m] = (unsigned int)f2bf(vn[2 * m]) | ((unsigned int)f2bf(vn[2 * m + 1]) << 16);
            ps[m] = (unsigned int)f2bf(vs[2 * m]) | ((unsigned int)f2bf(vs[2 * m + 1]) << 16);
        }
#pragma unroll
        for (int m = 0; m < 4; ++m) {
            const int boff = j * (LDK * 2) + (kc + 8 * m) * 2;   // 16B-aligned
            *reinterpret_cast<uint4*>(reinterpret_cast<char*>(wn_t) + boff)
                = make_uint4(pn[4 * m], pn[4 * m + 1], pn[4 * m + 2], pn[4 * m + 3]);
            *reinterpret_cast<uint4*>(reinterpret_cast<char*>(ws_t) + boff)
                = make_uint4(ps[4 * m], ps[4 * m + 1], ps[4 * m + 2], ps[4 * m + 3]);
        }
    }

    // ---- stage acc/nf tiles (fp32 -> bf16), coalesced float4 reads
    for (int i = tid; i < GROWS * (DIM / 4); i += 512) {
        const int r  = i >> 5;            // 32 float4 per row
        const int c4 = i & 31;
        const int row = row0 + r;
        float4 va = make_float4(0.f, 0.f, 0.f, 0.f), vb = va;
        if (row < NN) {
            va = *reinterpret_cast<const float4*>(acc + (size_t)row * DIM + c4 * 4);
            vb = *reinterpret_cast<const float4*>(nf  + (size_t)row * DIM + c4 * 4);
        }
        uint2 pa, pb;
        pa.x = (unsigned int)f2bf(va.x) | ((unsigned int)f2bf(va.y) << 16);
        pa.y = (unsigned int)f2bf(va.z) | ((unsigned int)f2bf(va.w) << 16);
        pb.x = (unsigned int)f2bf(vb.x) | ((unsigned int)f2bf(vb.y) << 16);
        pb.y = (unsigned int)f2bf(vb.z) | ((unsigned int)f2bf(vb.w) << 16);
        const int boff = r * (LDK * 2) + c4 * 8;                 // 8B-aligned
        *reinterpret_cast<uint2*>(reinterpret_cast<char*>(ac_t) + boff) = pa;
        *reinterpret_cast<uint2*>(reinterpret_cast<char*>(nf_t) + boff) = pb;
    }
    __syncthreads();

    // ---- compute: 8 waves
    const int w  = tid >> 6;
    const int l  = tid & 63;
    const int lr = l & 15;                // A row / B col / D col
    const int lg = l >> 4;                // k-group (8 bf16 each)
    const int wr = (w & 3) * 16;          // row strip in tile
    const int wc = (w >> 2) * 64;         // col base

    f32x4 accA[4], accN[4];
#pragma unroll
    for (int jt = 0; jt < 4; ++jt) {
        accA[jt] = (f32x4){0.f, 0.f, 0.f, 0.f};
        accN[jt] = (f32x4){0.f, 0.f, 0.f, 0.f};
    }

#pragma unroll
    for (int k0 = 0; k0 < DIM; k0 += 32) {
        const int arow = wr + lr;
        const int aoff = arow * (LDK * 2) + (k0 + 8 * lg) * 2;
        const bf16x8 aA = *reinterpret_cast<const bf16x8*>(
            reinterpret_cast<const char*>(ac_t) + aoff);
        const bf16x8 aN = *reinterpret_cast<const bf16x8*>(
            reinterpret_cast<const char*>(nf_t) + aoff);
#pragma unroll
        for (int jt = 0; jt < 4; ++jt) {
            const int brow = wc + jt * 16 + lr;
            const int boff = brow * (LDK * 2) + (k0 + 8 * lg) * 2;
            const bf16x8 bW = *reinterpret_cast<const bf16x8*>(
                reinterpret_cast<const char*>(wn_t) + boff);
            accA[jt] = __builtin_amdgcn_mfma_f32_16x16x32_bf16(aA, bW, accA[jt], 0, 0, 0);
            const bf16x8 bS = *reinterpret_cast<const bf16x8*>(
                reinterpret_cast<const char*>(ws_t) + boff);
            accN[jt] = __builtin_amdgcn_mfma_f32_16x16x32_bf16(aN, bS, accN[jt], 0, 0, 0);
        }
    }

    // ---- epilogue: out[row][col] = self + tanh(nbr + b)
#pragma unroll
    for (int jt = 0; jt < 4; ++jt) {
        const int col = wc + jt * 16 + lr;
        const float bv = bias[col];
#pragma unroll
        for (int r = 0; r < 4; ++r) {
            const int grow = row0 + wr + lg * 4 + r;
            if (grow < NN)
                out[(size_t)grow * DIM + col] = accN[jt][r] + tanhf(accA[jt][r] + bv);
        }
    }
}

extern "C" void kernel_launch(void* const* d_in, const int* in_sizes, int n_in,
                              void* d_out, int out_size, void* d_ws, size_t ws_size,
                              hipStream_t stream) {
    const float* nf  = (const float*)d_in[0];
    const void*  ei  = d_in[1];
    const float* wn  = (const float*)d_in[2];
    const float* wsf = (const float*)d_in[3];
    const float* bia = (const float*)d_in[4];
    float* out = (float*)d_out;
    int* ws_i = (int*)d_ws;

    const int gemm_blocks = (NN + GROWS - 1) / GROWS;   // 782
    const int edge_blocks = (NE + 255) / 256;           // 3125

    if (ws_size >= WS_REQ) {
        // ---- CSR path: no float atomics ----
        int* off      = ws_i + OFF_I;
        unsigned short* sorted = (unsigned short*)(ws_i + SORT_I);
        int* flag     = ws_i + FLAG_I;
        int* partials = ws_i + PART_I;

        detect_idx_width<<<1, 1, 0, stream>>>((const long long*)ei, flag);
        hipMemsetAsync(off, 0, (size_t)(NN + 1) * sizeof(int), stream);
        edge_hist<<<edge_blocks, 256, 0, stream>>>(ei, flag, off);
        scan_blocks<<<SCAN_NPB, 256, 0, stream>>>(off, partials);
        scan_partials<<<1, 256, 0, stream>>>(partials);
        scan_add<<<SCAN_NPB, 256, 0, stream>>>(off, partials);
        edge_fill<<<edge_blocks, 256, 0, stream>>>(ei, flag, off, sorted);
        gather_sum<<<(NN + 7) / 8, 256, 0, stream>>>(nf, off, sorted, out);
        fused_gemm<<<gemm_blocks, 512, 0, stream>>>(nf, out, wn, wsf, bia, out);
    } else {
        // ---- fallback: atomic scatter ----
        int* flag = ws_i;
        detect_idx_width<<<1, 1, 0, stream>>>((const long long*)ei, flag);
        hipMemsetAsync(out, 0, (size_t)NN * DIM * sizeof(float), stream);
        scatter_add<<<(NE * 32) / 256, 256, 0, stream>>>(nf, ei, flag, out);
        fused_gemm<<<gemm_blocks, 512, 0, stream>>>(nf, out, wn, wsf, bia, out);
    }
}